// Round 8
// baseline (186.569 us; speedup 1.0000x reference)
//
#include <hip/hip_runtime.h>

#define NPTS   25600
#define NB     16
#define NRES   320
#define OS     400
#define NCELL  (OS * OS)      // 160000
#define CAP    16
#define MAXOVF 4096

#define NJ     8              // lines per FFT block
#define FFTTH  512            // threads per FFT block
#define LSTRV  404            // LDS line stride in float2

// BETA = pi * sqrt((4/1.25*0.75)^2 - 0.8) = pi*sqrt(4.96)
#define BETA_F (3.14159265358979f * 2.22710574513201f)

__device__ __forceinline__ float bessel_i0f(float x) {
    float ax = fabsf(x);
    if (ax < 3.75f) {
        float t = (ax * ax) * (1.0f / 14.0625f);
        return 1.0f + t * (3.5156229f + t * (3.0899424f + t * (1.2067492f +
                     t * (0.2659732f + t * (0.0360768f + t * 0.0045813f)))));
    } else {
        float t = 3.75f / ax;
        return (expf(ax) * rsqrtf(ax)) *
               (0.39894228f + t * (0.01328592f + t * (0.00225319f + t * (-0.00157565f +
                t * (0.00916281f + t * (-0.02057706f + t * (0.02635537f +
                t * (-0.01647633f + t * 0.00392377f))))))));
    }
}

struct OvfEntry { int cell; int m; float w; float pad; };

// ---------------------------------------------------------------------------
// Fused: blocks [0,1600) bilinear-sample -> val[m][b]; blocks [1600,1700)
// compute KB taps -> slot-major ELL bins (cell = i1*OS + i0, j-major).
// ---------------------------------------------------------------------------
__global__ __launch_bounds__(256)
void k_sample_taps(const float* __restrict__ ksp,
                   const float* __restrict__ traj,
                   float2* __restrict__ val,
                   int* __restrict__ cursor,
                   float2* __restrict__ entries,
                   int* __restrict__ ovf_cnt,
                   OvfEntry* __restrict__ ovf)
{
    int blk = blockIdx.x;
    if (blk < 1600) {
        // ---- bilinear sample ----
        int gid = blk * 256 + threadIdx.x;
        int b = gid & 15;
        int m = gid >> 4;

        float tx = traj[2 * m + 0];
        float ty = traj[2 * m + 1];

        float px = (tx * (1.0f / 160.0f) + 1.0f) * 0.5f * 319.0f;
        float py = (ty * (1.0f / 160.0f) + 1.0f) * 0.5f * 319.0f;
        float fx0 = floorf(px), fy0 = floorf(py);
        int x0 = (int)fx0, y0 = (int)fy0;
        float wx1 = px - fx0, wy1 = py - fy0;
        float wx0 = 1.0f - wx1, wy0 = 1.0f - wy1;
        x0 = min(max(x0, 0), NRES - 1);
        y0 = min(max(y0, 0), NRES - 1);
        int x1 = min(x0 + 1, NRES - 1);
        int y1 = min(y0 + 1, NRES - 1);

        const float2* base = (const float2*)ksp + (size_t)b * NRES * NRES;
        float2 v00 = base[y0 * NRES + x0];
        float2 v01 = base[y0 * NRES + x1];
        float2 v10 = base[y1 * NRES + x0];
        float2 v11 = base[y1 * NRES + x1];
        float sr = (v00.x * wx0 + v01.x * wx1) * wy0 + (v10.x * wx0 + v11.x * wx1) * wy1;
        float si = (v00.y * wx0 + v01.y * wx1) * wy0 + (v10.y * wx0 + v11.y * wx1) * wy1;

        val[gid] = make_float2(sr, si);
    } else {
        // ---- KB taps -> ELL bins ----
        int m = (blk - 1600) * 256 + threadIdx.x;
        if (m >= NPTS) return;

        float tx = traj[2 * m + 0];
        float ty = traj[2 * m + 1];
        float c0 = tx * 1.25f + 200.0f;
        float c1 = ty * 1.25f + 200.0f;
        float s0 = ceilf(c0 - 2.0f);
        float s1 = ceilf(c1 - 2.0f);

        float w0[4], w1[4];
        int   i0[4], i1[4];
#pragma unroll
        for (int t = 0; t < 4; t++) {
            float id0 = s0 + (float)t;
            float d0 = (c0 - id0) * 0.5f;
            float t0 = fmaxf(1.0f - d0 * d0, 0.0f);
            w0[t] = bessel_i0f(BETA_F * sqrtf(t0)) * 0.25f;
            i0[t] = (((int)id0) + OS) % OS;

            float id1 = s1 + (float)t;
            float d1 = (c1 - id1) * 0.5f;
            float t1 = fmaxf(1.0f - d1 * d1, 0.0f);
            w1[t] = bessel_i0f(BETA_F * sqrtf(t1)) * 0.25f;
            i1[t] = (((int)id1) + OS) % OS;
        }

#pragma unroll
        for (int t0 = 0; t0 < 4; t0++) {
#pragma unroll
            for (int t1 = 0; t1 < 4; t1++) {
                int cell = i1[t1] * OS + i0[t0];
                float w = w0[t0] * w1[t1];
                int slot = atomicAdd(&cursor[cell], 1);
                if (slot < CAP) {
                    entries[(size_t)slot * NCELL + cell] = make_float2(__int_as_float(m), w);
                } else {
                    int oi = atomicAdd(ovf_cnt, 1);
                    if (oi < MAXOVF) { ovf[oi].cell = cell; ovf[oi].m = m; ovf[oi].w = w; }
                }
            }
        }
    }
}

// ---------------------------------------------------------------------------
// 400-pt +exponent DFT, radix 20x20, conjugate-PAIR outputs (see R7 notes).
// Pass A now FUSES the gather: each block builds its NJ grid rows directly
// from the ELL table (no materialized grid buffer).
// ---------------------------------------------------------------------------

__device__ __forceinline__ float apodf(int i) {
    float t = (float)(i - 160) * 0.031415926535897932f;  // pi*4/400
    float a = sqrtf(fmaxf(BETA_F * BETA_F - t * t, 1e-12f));
    return a / sinhf(a);
}

// Pass A: lines = grid rows (fixed j=i1), transform i0 axis -> At[b][uc][j].
__global__ __launch_bounds__(FFTTH)
void k_fft_pass_a(const int* __restrict__ cursor,
                  const float2* __restrict__ entries,
                  const float2* __restrict__ val,
                  const int* __restrict__ ovf_cnt,
                  const OvfEntry* __restrict__ ovf,
                  float* __restrict__ At)
{
    __shared__ float2 A[NJ * LSTRV];
    __shared__ float4 B4[NJ * 200];
    __shared__ float2 E20t[20];
    __shared__ float2 E400p[424];     // swizzled: entry t at t + (t>>4)
    int tid = threadIdx.x;
    int b = blockIdx.y;
    int j0 = blockIdx.x * NJ;

    for (int t = tid; t < 400; t += FFTTH) {
        float sn, cs;
        sincosf((float)t * 0.015707963267948966f, &sn, &cs);   // 2*pi/400
        E400p[t + (t >> 4)] = make_float2(cs, sn);
    }
    if (tid < 20) {
        float sn, cs;
        sincosf((float)tid * 0.3141592653589793f, &sn, &cs);   // 2*pi/20
        E20t[tid] = make_float2(cs, sn);
    }

    // fused gather: row j0+r, col i -> cell (j0+r)*OS + i
    for (int o = tid; o < NJ * OS; o += FFTTH) {
        int r = o / OS, i = o - r * OS;
        int cell = (j0 + r) * OS + i;
        int cnt_raw = cursor[cell];
        int cnt = min(cnt_raw, CAP);
        float ar = 0.f, ai = 0.f;
        for (int k = 0; k < cnt; k++) {
            float2 e = entries[(size_t)k * NCELL + cell];
            int m = __float_as_int(e.x);
            float w = e.y;
            float2 x = val[(size_t)m * NB + b];
            ar = fmaf(w, x.x, ar);
            ai = fmaf(w, x.y, ai);
        }
        if (cnt_raw > CAP) {                 // rare overflow fixup
            int n = min(*ovf_cnt, MAXOVF);
            for (int q = 0; q < n; q++) {
                if (ovf[q].cell == cell) {
                    float2 x = val[(size_t)ovf[q].m * NB + b];
                    ar = fmaf(ovf[q].w, x.x, ar);
                    ai = fmaf(ovf[q].w, x.y, ai);
                }
            }
        }
        A[r * LSTRV + i] = make_float2(ar, ai);
    }
    __syncthreads();

    // pairing over n1 (col = n2)
    for (int o = tid; o < NJ * 200; o += FFTTH) {
        int r = o / 200, rem = o - r * 200;
        int j = rem / 20, n2 = rem - j * 20;
        const float2* Al = &A[r * LSTRV];
        float4 outv;
        if (j == 0) {
            float2 a0 = Al[n2], a1 = Al[n2 + 200];
            outv = make_float4(a0.x, a0.y, a1.x, a1.y);
        } else {
            float2 a0 = Al[n2 + 20 * j], a1 = Al[n2 + 20 * (20 - j)];
            outv = make_float4(a0.x + a1.x, a0.y + a1.y, a0.x - a1.x, a0.y - a1.y);
        }
        B4[r * 200 + j * 20 + n2] = outv;
    }
    __syncthreads();

    // stage 1 (pair outputs) -> A
    for (int o = tid; o < NJ * 200; o += FFTTH) {
        int r = o / 200, rem = o - r * 200;
        int k1h = rem / 20, n2 = rem - k1h * 20;
        const float4* Bl = &B4[r * 200];
        float4 b0 = Bl[n2];
        float2* Ar_ = &A[r * LSTRV + 20 * n2];
        if (k1h == 0) {
            float b_r = b0.x + b0.z, b_i = b0.y + b0.w;
            float a0r = 0.f, a0i = 0.f, d0r = 0.f, d0i = 0.f;
#pragma unroll
            for (int j = 1; j <= 9; j++) {
                float4 P = Bl[j * 20 + n2];
                a0r += P.x; a0i += P.y;
                float sg = (j & 1) ? -1.f : 1.f;
                d0r = fmaf(sg, P.x, d0r); d0i = fmaf(sg, P.y, d0i);
            }
            Ar_[0] = make_float2(b_r + a0r, b_i + a0i);           // k1=0, tw=1
            int ti = 10 * n2;
            float2 tw = E400p[ti + (ti >> 4)];
            float xr = b_r + d0r, xi = b_i + d0i;                 // k1=10
            Ar_[10] = make_float2(xr * tw.x - xi * tw.y, xr * tw.y + xi * tw.x);
        } else {
            float sgn = (k1h & 1) ? -1.f : 1.f;
            float b_r = fmaf(sgn, b0.z, b0.x), b_i = fmaf(sgn, b0.w, b0.y);
            float2 ek = E20t[k1h];
            float c = ek.x, s = ek.y;
            float Asr = 0.f, Asi = 0.f, Bsr = 0.f, Bsi = 0.f;
#pragma unroll
            for (int j = 1; j <= 9; j++) {
                float4 P = Bl[j * 20 + n2];
                Asr = fmaf(c, P.x, Asr); Asi = fmaf(c, P.y, Asi);
                Bsr = fmaf(s, P.w, Bsr); Bsi = fmaf(s, P.z, Bsi);
                float cn = c * ek.x - s * ek.y;
                s = c * ek.y + s * ek.x;
                c = cn;
            }
            float x1r = b_r + Asr - Bsr, x1i = b_i + Asi + Bsi;   // k1h
            float x2r = b_r + Asr + Bsr, x2i = b_i + Asi - Bsi;   // 20-k1h
            int t1 = n2 * k1h;
            int t2 = n2 * (20 - k1h);
            float2 tw1 = E400p[t1 + (t1 >> 4)];
            float2 tw2 = E400p[t2 + (t2 >> 4)];
            Ar_[k1h]      = make_float2(x1r * tw1.x - x1i * tw1.y, x1r * tw1.y + x1i * tw1.x);
            Ar_[20 - k1h] = make_float2(x2r * tw2.x - x2i * tw2.y, x2r * tw2.y + x2i * tw2.x);
        }
    }
    __syncthreads();

    // pairing over n2 (col = k1)
    for (int o = tid; o < NJ * 200; o += FFTTH) {
        int r = o / 200, rem = o - r * 200;
        int j = rem / 20, k1 = rem - j * 20;
        const float2* Sl = &A[r * LSTRV];
        float4 outv;
        if (j == 0) {
            float2 a0 = Sl[k1], a1 = Sl[200 + k1];
            outv = make_float4(a0.x, a0.y, a1.x, a1.y);
        } else {
            float2 a0 = Sl[20 * j + k1], a1 = Sl[20 * (20 - j) + k1];
            outv = make_float4(a0.x + a1.x, a0.y + a1.y, a0.x - a1.x, a0.y - a1.y);
        }
        B4[r * 200 + j * 20 + k1] = outv;
    }
    __syncthreads();

    // stage 2 (pair outputs, crop-skip) -> A (compact 320)
    for (int o = tid; o < NJ * 180; o += FFTTH) {
        int r = o / 180, rem = o - r * 180;
        int k2h = rem / 20, k1 = rem - k2h * 20;
        const float4* Bl = &B4[r * 200];
        float4 b0 = Bl[k1];
        float2* Ar_ = &A[r * LSTRV];
        if (k2h == 0) {
            float b_r = b0.x + b0.z, b_i = b0.y + b0.w;
            float a0r = 0.f, a0i = 0.f;
#pragma unroll
            for (int j = 1; j <= 9; j++) {
                float4 P = Bl[j * 20 + k1];
                a0r += P.x; a0i += P.y;
            }
            Ar_[k1] = make_float2(b_r + a0r, b_i + a0i);          // vc = k1
        } else {
            float sgn = (k2h & 1) ? -1.f : 1.f;
            float b_r = fmaf(sgn, b0.z, b0.x), b_i = fmaf(sgn, b0.w, b0.y);
            float2 ek = E20t[k2h];
            float c = ek.x, s = ek.y;
            float Asr = 0.f, Asi = 0.f, Bsr = 0.f, Bsi = 0.f;
#pragma unroll
            for (int j = 1; j <= 9; j++) {
                float4 P = Bl[j * 20 + k1];
                Asr = fmaf(c, P.x, Asr); Asi = fmaf(c, P.y, Asi);
                Bsr = fmaf(s, P.w, Bsr); Bsi = fmaf(s, P.z, Bsi);
                float cn = c * ek.x - s * ek.y;
                s = c * ek.y + s * ek.x;
                c = cn;
            }
            if (k2h <= 7)
                Ar_[20 * k2h + k1] = make_float2(b_r + Asr - Bsr, b_i + Asi + Bsi);
            Ar_[320 - 20 * k2h + k1] = make_float2(b_r + Asr + Bsr, b_i + Asi - Bsi);
        }
    }
    __syncthreads();

    // transposed store: At[b][uc][j0+r]
    float2* At2 = (float2*)At;
    for (int o = tid; o < 320 * NJ; o += FFTTH) {
        int uc = o >> 3, r = o & 7;
        At2[((size_t)b * 320 + uc) * OS + j0 + r] = A[r * LSTRV + uc];
    }
}

// Pass B: lines = At rows (fixed uc), transform j axis; fused crop/shift/apod.
__global__ __launch_bounds__(FFTTH)
void k_fft_pass_b(const float* __restrict__ At, float* __restrict__ out)
{
    __shared__ float2 A[NJ * LSTRV];
    __shared__ float4 B4[NJ * 200];
    __shared__ float2 E20t[20];
    __shared__ float2 E400p[424];
    __shared__ float apodT[320];
    int tid = threadIdx.x;
    int b = blockIdx.y;
    int uc0 = blockIdx.x * NJ;

    for (int t = tid; t < 400; t += FFTTH) {
        float sn, cs;
        sincosf((float)t * 0.015707963267948966f, &sn, &cs);
        E400p[t + (t >> 4)] = make_float2(cs, sn);
    }
    if (tid < 20) {
        float sn, cs;
        sincosf((float)tid * 0.3141592653589793f, &sn, &cs);
        E20t[tid] = make_float2(cs, sn);
    }
    for (int t = tid; t < 320; t += FFTTH) apodT[t] = apodf(t);

    const float2* a = (const float2*)At + ((size_t)b * 320 + uc0) * OS;
    for (int o = tid; o < NJ * OS; o += FFTTH) {
        int r = o / OS, j = o - r * OS;
        A[r * LSTRV + j] = a[r * OS + j];
    }
    __syncthreads();

    for (int o = tid; o < NJ * 200; o += FFTTH) {
        int r = o / 200, rem = o - r * 200;
        int j = rem / 20, n2 = rem - j * 20;
        const float2* Al = &A[r * LSTRV];
        float4 outv;
        if (j == 0) {
            float2 a0 = Al[n2], a1 = Al[n2 + 200];
            outv = make_float4(a0.x, a0.y, a1.x, a1.y);
        } else {
            float2 a0 = Al[n2 + 20 * j], a1 = Al[n2 + 20 * (20 - j)];
            outv = make_float4(a0.x + a1.x, a0.y + a1.y, a0.x - a1.x, a0.y - a1.y);
        }
        B4[r * 200 + j * 20 + n2] = outv;
    }
    __syncthreads();

    for (int o = tid; o < NJ * 200; o += FFTTH) {
        int r = o / 200, rem = o - r * 200;
        int k1h = rem / 20, n2 = rem - k1h * 20;
        const float4* Bl = &B4[r * 200];
        float4 b0 = Bl[n2];
        float2* Ar_ = &A[r * LSTRV + 20 * n2];
        if (k1h == 0) {
            float b_r = b0.x + b0.z, b_i = b0.y + b0.w;
            float a0r = 0.f, a0i = 0.f, d0r = 0.f, d0i = 0.f;
#pragma unroll
            for (int j = 1; j <= 9; j++) {
                float4 P = Bl[j * 20 + n2];
                a0r += P.x; a0i += P.y;
                float sg = (j & 1) ? -1.f : 1.f;
                d0r = fmaf(sg, P.x, d0r); d0i = fmaf(sg, P.y, d0i);
            }
            Ar_[0] = make_float2(b_r + a0r, b_i + a0i);
            int ti = 10 * n2;
            float2 tw = E400p[ti + (ti >> 4)];
            float xr = b_r + d0r, xi = b_i + d0i;
            Ar_[10] = make_float2(xr * tw.x - xi * tw.y, xr * tw.y + xi * tw.x);
        } else {
            float sgn = (k1h & 1) ? -1.f : 1.f;
            float b_r = fmaf(sgn, b0.z, b0.x), b_i = fmaf(sgn, b0.w, b0.y);
            float2 ek = E20t[k1h];
            float c = ek.x, s = ek.y;
            float Asr = 0.f, Asi = 0.f, Bsr = 0.f, Bsi = 0.f;
#pragma unroll
            for (int j = 1; j <= 9; j++) {
                float4 P = Bl[j * 20 + n2];
                Asr = fmaf(c, P.x, Asr); Asi = fmaf(c, P.y, Asi);
                Bsr = fmaf(s, P.w, Bsr); Bsi = fmaf(s, P.z, Bsi);
                float cn = c * ek.x - s * ek.y;
                s = c * ek.y + s * ek.x;
                c = cn;
            }
            float x1r = b_r + Asr - Bsr, x1i = b_i + Asi + Bsi;
            float x2r = b_r + Asr + Bsr, x2i = b_i + Asi - Bsi;
            int t1 = n2 * k1h;
            int t2 = n2 * (20 - k1h);
            float2 tw1 = E400p[t1 + (t1 >> 4)];
            float2 tw2 = E400p[t2 + (t2 >> 4)];
            Ar_[k1h]      = make_float2(x1r * tw1.x - x1i * tw1.y, x1r * tw1.y + x1i * tw1.x);
            Ar_[20 - k1h] = make_float2(x2r * tw2.x - x2i * tw2.y, x2r * tw2.y + x2i * tw2.x);
        }
    }
    __syncthreads();

    for (int o = tid; o < NJ * 200; o += FFTTH) {
        int r = o / 200, rem = o - r * 200;
        int j = rem / 20, k1 = rem - j * 20;
        const float2* Sl = &A[r * LSTRV];
        float4 outv;
        if (j == 0) {
            float2 a0 = Sl[k1], a1 = Sl[200 + k1];
            outv = make_float4(a0.x, a0.y, a1.x, a1.y);
        } else {
            float2 a0 = Sl[20 * j + k1], a1 = Sl[20 * (20 - j) + k1];
            outv = make_float4(a0.x + a1.x, a0.y + a1.y, a0.x - a1.x, a0.y - a1.y);
        }
        B4[r * 200 + j * 20 + k1] = outv;
    }
    __syncthreads();

    // stage 2 + fused epilogue: y from line (uc0+r), x from freq vc.
    for (int o = tid; o < NJ * 180; o += FFTTH) {
        int r = o / 180, rem = o - r * 180;
        int k2h = rem / 20, k1 = rem - k2h * 20;
        const float4* Bl = &B4[r * 200];
        float4 b0 = Bl[k1];
        int y = uc0 + r + 160; if (y >= 320) y -= 320;
        float apy = (1.0f / 320.0f) * apodT[y];
        float* o0 = out + (((size_t)b * 2 + 0) * NRES + y) * NRES;
        float* o1 = out + (((size_t)b * 2 + 1) * NRES + y) * NRES;
        if (k2h == 0) {
            float b_r = b0.x + b0.z, b_i = b0.y + b0.w;
            float a0r = 0.f, a0i = 0.f;
#pragma unroll
            for (int j = 1; j <= 9; j++) {
                float4 P = Bl[j * 20 + k1];
                a0r += P.x; a0i += P.y;
            }
            int x = k1 + 160; if (x >= 320) x -= 320;
            float sg = ((x + y) & 1) ? -1.0f : 1.0f;
            float sc = sg * apy * apodT[x];
            o0[x] = (b_r + a0r) * sc;
            o1[x] = (b_i + a0i) * sc;
        } else {
            float sgn = (k2h & 1) ? -1.f : 1.f;
            float b_r = fmaf(sgn, b0.z, b0.x), b_i = fmaf(sgn, b0.w, b0.y);
            float2 ek = E20t[k2h];
            float c = ek.x, s = ek.y;
            float Asr = 0.f, Asi = 0.f, Bsr = 0.f, Bsi = 0.f;
#pragma unroll
            for (int j = 1; j <= 9; j++) {
                float4 P = Bl[j * 20 + k1];
                Asr = fmaf(c, P.x, Asr); Asi = fmaf(c, P.y, Asi);
                Bsr = fmaf(s, P.w, Bsr); Bsi = fmaf(s, P.z, Bsi);
                float cn = c * ek.x - s * ek.y;
                s = c * ek.y + s * ek.x;
                c = cn;
            }
            if (k2h <= 7) {
                int vc = 20 * k2h + k1;
                int x = vc + 160; if (x >= 320) x -= 320;
                float sg = ((x + y) & 1) ? -1.0f : 1.0f;
                float sc = sg * apy * apodT[x];
                o0[x] = (b_r + Asr - Bsr) * sc;
                o1[x] = (b_i + Asi + Bsi) * sc;
            }
            {
                int vc = 320 - 20 * k2h + k1;
                int x = vc + 160; if (x >= 320) x -= 320;
                float sg = ((x + y) & 1) ? -1.0f : 1.0f;
                float sc = sg * apy * apodT[x];
                o0[x] = (b_r + Asr + Bsr) * sc;
                o1[x] = (b_i + Asi - Bsi) * sc;
            }
        }
    }
}

extern "C" void kernel_launch(void* const* d_in, const int* in_sizes, int n_in,
                              void* d_out, int out_size, void* d_ws, size_t ws_size,
                              hipStream_t stream) {
    const float* ksp  = (const float*)d_in[0];
    const float* traj = (const float*)d_in[1];
    float* out = (float*)d_out;

    // ws layout (floats). NOTE: entries must NOT alias At (both live in pass A).
    //   At      : NB*320*OS*2 = 4,096,000 floats (16.38 MB)
    //   entries : CAP*NCELL float2 (20.48 MB)
    //   val     : NPTS*NB float2 (3.28 MB)
    //   cursor  : NCELL ints; ovf_cnt; ovf
    float* At = (float*)d_ws;
    float2* entries = (float2*)(At + (size_t)NB * 320 * OS * 2);
    float2* val = (float2*)(entries + (size_t)CAP * NCELL);
    int* cursor  = (int*)(val + (size_t)NPTS * NB);
    int* ovf_cnt = cursor + NCELL;
    OvfEntry* ovf = (OvfEntry*)(ovf_cnt + 16);

    hipMemsetAsync(cursor, 0, (NCELL + 16) * sizeof(int), stream);

    k_sample_taps<<<dim3(1700), 256, 0, stream>>>(ksp, traj, val, cursor, entries, ovf_cnt, ovf);
    k_fft_pass_a <<<dim3(OS / NJ, NB),  FFTTH, 0, stream>>>(cursor, entries, val, ovf_cnt, ovf, At);
    k_fft_pass_b <<<dim3(320 / NJ, NB), FFTTH, 0, stream>>>(At, out);
}

// Round 9
// 149.605 us; speedup vs baseline: 1.2471x; 1.2471x over previous
//
#include <hip/hip_runtime.h>

#define NPTS   25600
#define NB     16
#define NRES   320
#define OS     400
#define NCELL  (OS * OS)      // 160000
#define CAP    16
#define MAXOVF 4096

#define NJ     8              // lines per FFT block
#define FFTTH  512            // threads per FFT block
#define LSTRV  404            // LDS line stride in float2

// BETA = pi * sqrt((4/1.25*0.75)^2 - 0.8) = pi*sqrt(4.96)
#define BETA_F (3.14159265358979f * 2.22710574513201f)

__device__ __forceinline__ float bessel_i0f(float x) {
    float ax = fabsf(x);
    if (ax < 3.75f) {
        float t = (ax * ax) * (1.0f / 14.0625f);
        return 1.0f + t * (3.5156229f + t * (3.0899424f + t * (1.2067492f +
                     t * (0.2659732f + t * (0.0360768f + t * 0.0045813f)))));
    } else {
        float t = 3.75f / ax;
        return (expf(ax) * rsqrtf(ax)) *
               (0.39894228f + t * (0.01328592f + t * (0.00225319f + t * (-0.00157565f +
                t * (0.00916281f + t * (-0.02057706f + t * (0.02635537f +
                t * (-0.01647633f + t * 0.00392377f))))))));
    }
}

struct OvfEntry { int cell; int m; float w; float pad; };

// ---------------------------------------------------------------------------
// Fused: blocks [0,1600) bilinear-sample -> val[m][b]; blocks [1600,1700)
// compute KB taps -> slot-major ELL bins (cell = i1*OS + i0, j-major).
// ---------------------------------------------------------------------------
__global__ __launch_bounds__(256)
void k_sample_taps(const float* __restrict__ ksp,
                   const float* __restrict__ traj,
                   float2* __restrict__ val,
                   int* __restrict__ cursor,
                   float2* __restrict__ entries,
                   int* __restrict__ ovf_cnt,
                   OvfEntry* __restrict__ ovf)
{
    int blk = blockIdx.x;
    if (blk < 1600) {
        int gid = blk * 256 + threadIdx.x;
        int b = gid & 15;
        int m = gid >> 4;

        float tx = traj[2 * m + 0];
        float ty = traj[2 * m + 1];

        float px = (tx * (1.0f / 160.0f) + 1.0f) * 0.5f * 319.0f;
        float py = (ty * (1.0f / 160.0f) + 1.0f) * 0.5f * 319.0f;
        float fx0 = floorf(px), fy0 = floorf(py);
        int x0 = (int)fx0, y0 = (int)fy0;
        float wx1 = px - fx0, wy1 = py - fy0;
        float wx0 = 1.0f - wx1, wy0 = 1.0f - wy1;
        x0 = min(max(x0, 0), NRES - 1);
        y0 = min(max(y0, 0), NRES - 1);
        int x1 = min(x0 + 1, NRES - 1);
        int y1 = min(y0 + 1, NRES - 1);

        const float2* base = (const float2*)ksp + (size_t)b * NRES * NRES;
        float2 v00 = base[y0 * NRES + x0];
        float2 v01 = base[y0 * NRES + x1];
        float2 v10 = base[y1 * NRES + x0];
        float2 v11 = base[y1 * NRES + x1];
        float sr = (v00.x * wx0 + v01.x * wx1) * wy0 + (v10.x * wx0 + v11.x * wx1) * wy1;
        float si = (v00.y * wx0 + v01.y * wx1) * wy0 + (v10.y * wx0 + v11.y * wx1) * wy1;

        val[gid] = make_float2(sr, si);
    } else {
        int m = (blk - 1600) * 256 + threadIdx.x;
        if (m >= NPTS) return;

        float tx = traj[2 * m + 0];
        float ty = traj[2 * m + 1];
        float c0 = tx * 1.25f + 200.0f;
        float c1 = ty * 1.25f + 200.0f;
        float s0 = ceilf(c0 - 2.0f);
        float s1 = ceilf(c1 - 2.0f);

        float w0[4], w1[4];
        int   i0[4], i1[4];
#pragma unroll
        for (int t = 0; t < 4; t++) {
            float id0 = s0 + (float)t;
            float d0 = (c0 - id0) * 0.5f;
            float t0 = fmaxf(1.0f - d0 * d0, 0.0f);
            w0[t] = bessel_i0f(BETA_F * sqrtf(t0)) * 0.25f;
            i0[t] = (((int)id0) + OS) % OS;

            float id1 = s1 + (float)t;
            float d1 = (c1 - id1) * 0.5f;
            float t1 = fmaxf(1.0f - d1 * d1, 0.0f);
            w1[t] = bessel_i0f(BETA_F * sqrtf(t1)) * 0.25f;
            i1[t] = (((int)id1) + OS) % OS;
        }

#pragma unroll
        for (int t0 = 0; t0 < 4; t0++) {
#pragma unroll
            for (int t1 = 0; t1 < 4; t1++) {
                int cell = i1[t1] * OS + i0[t0];
                float w = w0[t0] * w1[t1];
                int slot = atomicAdd(&cursor[cell], 1);
                if (slot < CAP) {
                    entries[(size_t)slot * NCELL + cell] = make_float2(__int_as_float(m), w);
                } else {
                    int oi = atomicAdd(ovf_cnt, 1);
                    if (oi < MAXOVF) { ovf[oi].cell = cell; ovf[oi].m = m; ovf[oi].w = w; }
                }
            }
        }
    }
}

// ---------------------------------------------------------------------------
// Gather-SpMM: one thread per cell, all 16 batches in float4 registers;
// entries read once per cell, val rows are 128 B contiguous; overflow folded.
// ---------------------------------------------------------------------------
__global__ __launch_bounds__(256)
void k_gather(const int* __restrict__ cursor,
              const float2* __restrict__ entries,
              const float4* __restrict__ val4,   // (25600, 8 float4)
              float2* __restrict__ grid,
              const int* __restrict__ ovf_cnt,
              const OvfEntry* __restrict__ ovf)
{
    int cell = blockIdx.x * blockDim.x + threadIdx.x;
    if (cell >= NCELL) return;
    int cnt_raw = cursor[cell];
    int cnt = min(cnt_raw, CAP);

    float4 acc[8];
#pragma unroll
    for (int q = 0; q < 8; q++) acc[q] = make_float4(0.f, 0.f, 0.f, 0.f);

    for (int k = 0; k < cnt; k++) {
        float2 e = entries[(size_t)k * NCELL + cell];
        int m = __float_as_int(e.x);
        float w = e.y;
        const float4* v = val4 + (size_t)m * 8;
#pragma unroll
        for (int q = 0; q < 8; q++) {
            float4 x = v[q];
            acc[q].x = fmaf(w, x.x, acc[q].x);
            acc[q].y = fmaf(w, x.y, acc[q].y);
            acc[q].z = fmaf(w, x.z, acc[q].z);
            acc[q].w = fmaf(w, x.w, acc[q].w);
        }
    }

    if (cnt_raw > CAP) {                    // rare: scan overflow list
        int n = min(*ovf_cnt, MAXOVF);
        for (int i = 0; i < n; i++) {
            if (ovf[i].cell != cell) continue;
            int m = ovf[i].m;
            float w = ovf[i].w;
            const float4* v = val4 + (size_t)m * 8;
#pragma unroll
            for (int q = 0; q < 8; q++) {
                float4 x = v[q];
                acc[q].x = fmaf(w, x.x, acc[q].x);
                acc[q].y = fmaf(w, x.y, acc[q].y);
                acc[q].z = fmaf(w, x.z, acc[q].z);
                acc[q].w = fmaf(w, x.w, acc[q].w);
            }
        }
    }

#pragma unroll
    for (int q = 0; q < 8; q++) {
        grid[(size_t)(2 * q + 0) * NCELL + cell] = make_float2(acc[q].x, acc[q].y);
        grid[(size_t)(2 * q + 1) * NCELL + cell] = make_float2(acc[q].z, acc[q].w);
    }
}

// ---------------------------------------------------------------------------
// 400-pt +exponent DFT, radix 20x20, conjugate-PAIR outputs.
// ---------------------------------------------------------------------------

__device__ __forceinline__ float apodf(int i) {
    float t = (float)(i - 160) * 0.031415926535897932f;  // pi*4/400
    float a = sqrtf(fmaxf(BETA_F * BETA_F - t * t, 1e-12f));
    return a / sinhf(a);
}

// Pass A: lines = grid rows (fixed j=i1), transform i0 axis -> At[b][uc][j].
__global__ __launch_bounds__(FFTTH)
void k_fft_pass_a(const float* __restrict__ grid, float* __restrict__ At)
{
    __shared__ float2 A[NJ * LSTRV];
    __shared__ float4 B4[NJ * 200];
    __shared__ float2 E20t[20];
    __shared__ float2 E400p[424];     // swizzled: entry t at t + (t>>4)
    int tid = threadIdx.x;
    int b = blockIdx.y;
    int j0 = blockIdx.x * NJ;

    for (int t = tid; t < 400; t += FFTTH) {
        float sn, cs;
        sincosf((float)t * 0.015707963267948966f, &sn, &cs);   // 2*pi/400
        E400p[t + (t >> 4)] = make_float2(cs, sn);
    }
    if (tid < 20) {
        float sn, cs;
        sincosf((float)tid * 0.3141592653589793f, &sn, &cs);   // 2*pi/20
        E20t[tid] = make_float2(cs, sn);
    }
    // float4 staging: each line = 200 float4
    const float4* g4 = (const float4*)(grid + ((size_t)b * NCELL + (size_t)j0 * OS) * 2);
    for (int o = tid; o < NJ * 200; o += FFTTH) {
        int r = o / 200, q = o - r * 200;
        *((float4*)&A[r * LSTRV] + q) = g4[r * 200 + q];
    }
    __syncthreads();

    // pairing over n1 (col = n2)
    for (int o = tid; o < NJ * 200; o += FFTTH) {
        int r = o / 200, rem = o - r * 200;
        int j = rem / 20, n2 = rem - j * 20;
        const float2* Al = &A[r * LSTRV];
        float4 outv;
        if (j == 0) {
            float2 a0 = Al[n2], a1 = Al[n2 + 200];
            outv = make_float4(a0.x, a0.y, a1.x, a1.y);
        } else {
            float2 a0 = Al[n2 + 20 * j], a1 = Al[n2 + 20 * (20 - j)];
            outv = make_float4(a0.x + a1.x, a0.y + a1.y, a0.x - a1.x, a0.y - a1.y);
        }
        B4[r * 200 + j * 20 + n2] = outv;
    }
    __syncthreads();

    // stage 1 (pair outputs) -> A
    for (int o = tid; o < NJ * 200; o += FFTTH) {
        int r = o / 200, rem = o - r * 200;
        int k1h = rem / 20, n2 = rem - k1h * 20;
        const float4* Bl = &B4[r * 200];
        float4 b0 = Bl[n2];
        float2* Ar_ = &A[r * LSTRV + 20 * n2];
        if (k1h == 0) {
            float b_r = b0.x + b0.z, b_i = b0.y + b0.w;
            float a0r = 0.f, a0i = 0.f, d0r = 0.f, d0i = 0.f;
#pragma unroll
            for (int j = 1; j <= 9; j++) {
                float4 P = Bl[j * 20 + n2];
                a0r += P.x; a0i += P.y;
                float sg = (j & 1) ? -1.f : 1.f;
                d0r = fmaf(sg, P.x, d0r); d0i = fmaf(sg, P.y, d0i);
            }
            Ar_[0] = make_float2(b_r + a0r, b_i + a0i);           // k1=0, tw=1
            int ti = 10 * n2;
            float2 tw = E400p[ti + (ti >> 4)];
            float xr = b_r + d0r, xi = b_i + d0i;                 // k1=10
            Ar_[10] = make_float2(xr * tw.x - xi * tw.y, xr * tw.y + xi * tw.x);
        } else {
            float sgn = (k1h & 1) ? -1.f : 1.f;
            float b_r = fmaf(sgn, b0.z, b0.x), b_i = fmaf(sgn, b0.w, b0.y);
            float2 ek = E20t[k1h];
            float c = ek.x, s = ek.y;
            float Asr = 0.f, Asi = 0.f, Bsr = 0.f, Bsi = 0.f;
#pragma unroll
            for (int j = 1; j <= 9; j++) {
                float4 P = Bl[j * 20 + n2];
                Asr = fmaf(c, P.x, Asr); Asi = fmaf(c, P.y, Asi);
                Bsr = fmaf(s, P.w, Bsr); Bsi = fmaf(s, P.z, Bsi);
                float cn = c * ek.x - s * ek.y;
                s = c * ek.y + s * ek.x;
                c = cn;
            }
            float x1r = b_r + Asr - Bsr, x1i = b_i + Asi + Bsi;   // k1h
            float x2r = b_r + Asr + Bsr, x2i = b_i + Asi - Bsi;   // 20-k1h
            int t1 = n2 * k1h;
            int t2 = n2 * (20 - k1h);
            float2 tw1 = E400p[t1 + (t1 >> 4)];
            float2 tw2 = E400p[t2 + (t2 >> 4)];
            Ar_[k1h]      = make_float2(x1r * tw1.x - x1i * tw1.y, x1r * tw1.y + x1i * tw1.x);
            Ar_[20 - k1h] = make_float2(x2r * tw2.x - x2i * tw2.y, x2r * tw2.y + x2i * tw2.x);
        }
    }
    __syncthreads();

    // pairing over n2 (col = k1)
    for (int o = tid; o < NJ * 200; o += FFTTH) {
        int r = o / 200, rem = o - r * 200;
        int j = rem / 20, k1 = rem - j * 20;
        const float2* Sl = &A[r * LSTRV];
        float4 outv;
        if (j == 0) {
            float2 a0 = Sl[k1], a1 = Sl[200 + k1];
            outv = make_float4(a0.x, a0.y, a1.x, a1.y);
        } else {
            float2 a0 = Sl[20 * j + k1], a1 = Sl[20 * (20 - j) + k1];
            outv = make_float4(a0.x + a1.x, a0.y + a1.y, a0.x - a1.x, a0.y - a1.y);
        }
        B4[r * 200 + j * 20 + k1] = outv;
    }
    __syncthreads();

    // stage 2 (pair outputs, crop-skip) -> A (compact 320)
    for (int o = tid; o < NJ * 180; o += FFTTH) {
        int r = o / 180, rem = o - r * 180;
        int k2h = rem / 20, k1 = rem - k2h * 20;
        const float4* Bl = &B4[r * 200];
        float4 b0 = Bl[k1];
        float2* Ar_ = &A[r * LSTRV];
        if (k2h == 0) {
            float b_r = b0.x + b0.z, b_i = b0.y + b0.w;
            float a0r = 0.f, a0i = 0.f;
#pragma unroll
            for (int j = 1; j <= 9; j++) {
                float4 P = Bl[j * 20 + k1];
                a0r += P.x; a0i += P.y;
            }
            Ar_[k1] = make_float2(b_r + a0r, b_i + a0i);          // vc = k1
        } else {
            float sgn = (k2h & 1) ? -1.f : 1.f;
            float b_r = fmaf(sgn, b0.z, b0.x), b_i = fmaf(sgn, b0.w, b0.y);
            float2 ek = E20t[k2h];
            float c = ek.x, s = ek.y;
            float Asr = 0.f, Asi = 0.f, Bsr = 0.f, Bsi = 0.f;
#pragma unroll
            for (int j = 1; j <= 9; j++) {
                float4 P = Bl[j * 20 + k1];
                Asr = fmaf(c, P.x, Asr); Asi = fmaf(c, P.y, Asi);
                Bsr = fmaf(s, P.w, Bsr); Bsi = fmaf(s, P.z, Bsi);
                float cn = c * ek.x - s * ek.y;
                s = c * ek.y + s * ek.x;
                c = cn;
            }
            if (k2h <= 7)
                Ar_[20 * k2h + k1] = make_float2(b_r + Asr - Bsr, b_i + Asi + Bsi);
            Ar_[320 - 20 * k2h + k1] = make_float2(b_r + Asr + Bsr, b_i + Asi - Bsi);
        }
    }
    __syncthreads();

    // transposed store: At[b][uc][j0+r]
    float2* At2 = (float2*)At;
    for (int o = tid; o < 320 * NJ; o += FFTTH) {
        int uc = o >> 3, r = o & 7;
        At2[((size_t)b * 320 + uc) * OS + j0 + r] = A[r * LSTRV + uc];
    }
}

// Pass B: lines = At rows (fixed uc), transform j axis; fused crop/shift/apod.
__global__ __launch_bounds__(FFTTH)
void k_fft_pass_b(const float* __restrict__ At, float* __restrict__ out)
{
    __shared__ float2 A[NJ * LSTRV];
    __shared__ float4 B4[NJ * 200];
    __shared__ float2 E20t[20];
    __shared__ float2 E400p[424];
    __shared__ float apodT[320];
    int tid = threadIdx.x;
    int b = blockIdx.y;
    int uc0 = blockIdx.x * NJ;

    for (int t = tid; t < 400; t += FFTTH) {
        float sn, cs;
        sincosf((float)t * 0.015707963267948966f, &sn, &cs);
        E400p[t + (t >> 4)] = make_float2(cs, sn);
    }
    if (tid < 20) {
        float sn, cs;
        sincosf((float)tid * 0.3141592653589793f, &sn, &cs);
        E20t[tid] = make_float2(cs, sn);
    }
    for (int t = tid; t < 320; t += FFTTH) apodT[t] = apodf(t);

    const float4* a4 = (const float4*)(At + ((size_t)b * 320 + uc0) * OS * 2);
    for (int o = tid; o < NJ * 200; o += FFTTH) {
        int r = o / 200, q = o - r * 200;
        *((float4*)&A[r * LSTRV] + q) = a4[r * 200 + q];
    }
    __syncthreads();

    for (int o = tid; o < NJ * 200; o += FFTTH) {
        int r = o / 200, rem = o - r * 200;
        int j = rem / 20, n2 = rem - j * 20;
        const float2* Al = &A[r * LSTRV];
        float4 outv;
        if (j == 0) {
            float2 a0 = Al[n2], a1 = Al[n2 + 200];
            outv = make_float4(a0.x, a0.y, a1.x, a1.y);
        } else {
            float2 a0 = Al[n2 + 20 * j], a1 = Al[n2 + 20 * (20 - j)];
            outv = make_float4(a0.x + a1.x, a0.y + a1.y, a0.x - a1.x, a0.y - a1.y);
        }
        B4[r * 200 + j * 20 + n2] = outv;
    }
    __syncthreads();

    for (int o = tid; o < NJ * 200; o += FFTTH) {
        int r = o / 200, rem = o - r * 200;
        int k1h = rem / 20, n2 = rem - k1h * 20;
        const float4* Bl = &B4[r * 200];
        float4 b0 = Bl[n2];
        float2* Ar_ = &A[r * LSTRV + 20 * n2];
        if (k1h == 0) {
            float b_r = b0.x + b0.z, b_i = b0.y + b0.w;
            float a0r = 0.f, a0i = 0.f, d0r = 0.f, d0i = 0.f;
#pragma unroll
            for (int j = 1; j <= 9; j++) {
                float4 P = Bl[j * 20 + n2];
                a0r += P.x; a0i += P.y;
                float sg = (j & 1) ? -1.f : 1.f;
                d0r = fmaf(sg, P.x, d0r); d0i = fmaf(sg, P.y, d0i);
            }
            Ar_[0] = make_float2(b_r + a0r, b_i + a0i);
            int ti = 10 * n2;
            float2 tw = E400p[ti + (ti >> 4)];
            float xr = b_r + d0r, xi = b_i + d0i;
            Ar_[10] = make_float2(xr * tw.x - xi * tw.y, xr * tw.y + xi * tw.x);
        } else {
            float sgn = (k1h & 1) ? -1.f : 1.f;
            float b_r = fmaf(sgn, b0.z, b0.x), b_i = fmaf(sgn, b0.w, b0.y);
            float2 ek = E20t[k1h];
            float c = ek.x, s = ek.y;
            float Asr = 0.f, Asi = 0.f, Bsr = 0.f, Bsi = 0.f;
#pragma unroll
            for (int j = 1; j <= 9; j++) {
                float4 P = Bl[j * 20 + n2];
                Asr = fmaf(c, P.x, Asr); Asi = fmaf(c, P.y, Asi);
                Bsr = fmaf(s, P.w, Bsr); Bsi = fmaf(s, P.z, Bsi);
                float cn = c * ek.x - s * ek.y;
                s = c * ek.y + s * ek.x;
                c = cn;
            }
            float x1r = b_r + Asr - Bsr, x1i = b_i + Asi + Bsi;
            float x2r = b_r + Asr + Bsr, x2i = b_i + Asi - Bsi;
            int t1 = n2 * k1h;
            int t2 = n2 * (20 - k1h);
            float2 tw1 = E400p[t1 + (t1 >> 4)];
            float2 tw2 = E400p[t2 + (t2 >> 4)];
            Ar_[k1h]      = make_float2(x1r * tw1.x - x1i * tw1.y, x1r * tw1.y + x1i * tw1.x);
            Ar_[20 - k1h] = make_float2(x2r * tw2.x - x2i * tw2.y, x2r * tw2.y + x2i * tw2.x);
        }
    }
    __syncthreads();

    for (int o = tid; o < NJ * 200; o += FFTTH) {
        int r = o / 200, rem = o - r * 200;
        int j = rem / 20, k1 = rem - j * 20;
        const float2* Sl = &A[r * LSTRV];
        float4 outv;
        if (j == 0) {
            float2 a0 = Sl[k1], a1 = Sl[200 + k1];
            outv = make_float4(a0.x, a0.y, a1.x, a1.y);
        } else {
            float2 a0 = Sl[20 * j + k1], a1 = Sl[20 * (20 - j) + k1];
            outv = make_float4(a0.x + a1.x, a0.y + a1.y, a0.x - a1.x, a0.y - a1.y);
        }
        B4[r * 200 + j * 20 + k1] = outv;
    }
    __syncthreads();

    // stage 2 + fused epilogue: y from line (uc0+r), x from freq vc.
    for (int o = tid; o < NJ * 180; o += FFTTH) {
        int r = o / 180, rem = o - r * 180;
        int k2h = rem / 20, k1 = rem - k2h * 20;
        const float4* Bl = &B4[r * 200];
        float4 b0 = Bl[k1];
        int y = uc0 + r + 160; if (y >= 320) y -= 320;
        float apy = (1.0f / 320.0f) * apodT[y];
        float* o0 = out + (((size_t)b * 2 + 0) * NRES + y) * NRES;
        float* o1 = out + (((size_t)b * 2 + 1) * NRES + y) * NRES;
        if (k2h == 0) {
            float b_r = b0.x + b0.z, b_i = b0.y + b0.w;
            float a0r = 0.f, a0i = 0.f;
#pragma unroll
            for (int j = 1; j <= 9; j++) {
                float4 P = Bl[j * 20 + k1];
                a0r += P.x; a0i += P.y;
            }
            int x = k1 + 160; if (x >= 320) x -= 320;
            float sg = ((x + y) & 1) ? -1.0f : 1.0f;
            float sc = sg * apy * apodT[x];
            o0[x] = (b_r + a0r) * sc;
            o1[x] = (b_i + a0i) * sc;
        } else {
            float sgn = (k2h & 1) ? -1.f : 1.f;
            float b_r = fmaf(sgn, b0.z, b0.x), b_i = fmaf(sgn, b0.w, b0.y);
            float2 ek = E20t[k2h];
            float c = ek.x, s = ek.y;
            float Asr = 0.f, Asi = 0.f, Bsr = 0.f, Bsi = 0.f;
#pragma unroll
            for (int j = 1; j <= 9; j++) {
                float4 P = Bl[j * 20 + k1];
                Asr = fmaf(c, P.x, Asr); Asi = fmaf(c, P.y, Asi);
                Bsr = fmaf(s, P.w, Bsr); Bsi = fmaf(s, P.z, Bsi);
                float cn = c * ek.x - s * ek.y;
                s = c * ek.y + s * ek.x;
                c = cn;
            }
            if (k2h <= 7) {
                int vc = 20 * k2h + k1;
                int x = vc + 160; if (x >= 320) x -= 320;
                float sg = ((x + y) & 1) ? -1.0f : 1.0f;
                float sc = sg * apy * apodT[x];
                o0[x] = (b_r + Asr - Bsr) * sc;
                o1[x] = (b_i + Asi + Bsi) * sc;
            }
            {
                int vc = 320 - 20 * k2h + k1;
                int x = vc + 160; if (x >= 320) x -= 320;
                float sg = ((x + y) & 1) ? -1.0f : 1.0f;
                float sc = sg * apy * apodT[x];
                o0[x] = (b_r + Asr + Bsr) * sc;
                o1[x] = (b_i + Asi - Bsi) * sc;
            }
        }
    }
}

extern "C" void kernel_launch(void* const* d_in, const int* in_sizes, int n_in,
                              void* d_out, int out_size, void* d_ws, size_t ws_size,
                              hipStream_t stream) {
    const float* ksp  = (const float*)d_in[0];
    const float* traj = (const float*)d_in[1];
    float* out = (float*)d_out;

    // ws layout (floats):
    //   grid    : NB*NCELL*2 = 5,120,000 (20.48 MB)
    //   At      : NB*320*OS*2 = 4,096,000 (16.38 MB)
    //   entries : CAP*NCELL float2 (20.48 MB)
    //   val     : NPTS*NB float2 (3.28 MB)
    //   cursor  : NCELL ints; ovf_cnt; ovf
    float* grid = (float*)d_ws;
    float* At   = grid + (size_t)NB * NCELL * 2;
    float2* entries = (float2*)(At + (size_t)NB * 320 * OS * 2);
    float2* val = (float2*)(entries + (size_t)CAP * NCELL);
    int* cursor  = (int*)(val + (size_t)NPTS * NB);
    int* ovf_cnt = cursor + NCELL;
    OvfEntry* ovf = (OvfEntry*)(ovf_cnt + 16);

    hipMemsetAsync(cursor, 0, (NCELL + 16) * sizeof(int), stream);

    k_sample_taps<<<dim3(1700), 256, 0, stream>>>(ksp, traj, val, cursor, entries, ovf_cnt, ovf);
    k_gather     <<<dim3((NCELL + 255) / 256), 256, 0, stream>>>(cursor, entries, (const float4*)val,
                                                                 (float2*)grid, ovf_cnt, ovf);
    k_fft_pass_a <<<dim3(OS / NJ, NB),  FFTTH, 0, stream>>>(grid, At);
    k_fft_pass_b <<<dim3(320 / NJ, NB), FFTTH, 0, stream>>>(At, out);
}